// Round 2
// baseline (4853.137 us; speedup 1.0000x reference)
//
#include <hip/hip_runtime.h>
#include <hip/hip_bf16.h>

// bidirLSTM: T=8192 seq, V=1e6 vocab, E=60 emb, D=60 hidden, C=5 out.
// ALL tensor inputs are float32 (per reference setup_inputs); tokens int32.
// Output: float32[5].
//
// kernel1: gates_x = emb[tokens] @ Wxh.T + (bxh+bhh), for both directions,
//          stored permuted into the scan kernel's lane order (16 MB in d_ws).
// kernel2: sequential scan, 1 block/dir, 4 waves; lane quad holds the 4 gates
//          of one hidden unit d; h double-buffered in LDS, 1 barrier/step.
// kernel3: out = Why_L @ h_L + Why_R @ h_R.

#define T_LEN 8192
#define E_DIM 60
#define D_DIM 60
#define TB    32       // timesteps per block in gates kernel

// ---------------------------------------------------------------------------
// Kernel 1: gxp[dir][t][p] = gates_x[dir][t][gate*60+dd] + (bxh+bhh)[j]
// where p = w*64 + l, gate = l&3, dd = 15*w + (l>>2)  (the scan's lane order).
// ---------------------------------------------------------------------------
__global__ __launch_bounds__(256) void gates_kernel(
    const int*   __restrict__ tokens,
    const float* __restrict__ emb,
    const float* __restrict__ WxhL,
    const float* __restrict__ bxhL,
    const float* __restrict__ bhhL,
    const float* __restrict__ WxhR,
    const float* __restrict__ bxhR,
    const float* __restrict__ bhhR,
    float* __restrict__ gxp)
{
    const int dir = blockIdx.y;
    const float* Wxh = dir ? WxhR : WxhL;
    const float* bxh = dir ? bxhR : bxhL;
    const float* bhh = dir ? bhhR : bhhL;

    const int p = threadIdx.x;
    const int w = p >> 6, l = p & 63;
    const int gate = l & 3;
    const int dd = 15 * w + (l >> 2);
    const bool act = (l < 60);
    const int j = gate * 60 + dd;

    float wx[E_DIM];
    float bj = 0.f;
    if (act) {
        const float4* row = (const float4*)(Wxh + (size_t)j * E_DIM); // j*240 B, 16B-aligned
        #pragma unroll
        for (int i = 0; i < 15; ++i) {
            float4 v = row[i];
            wx[4 * i]     = v.x;
            wx[4 * i + 1] = v.y;
            wx[4 * i + 2] = v.z;
            wx[4 * i + 3] = v.w;
        }
        bj = bxh[j] + bhh[j];
    }

    __shared__ float xs[64];
    const int t0 = blockIdx.x * TB;
    for (int tt = 0; tt < TB; ++tt) {
        const int t = t0 + tt;
        const int idx = dir ? (T_LEN - 1 - t) : t;
        const int tok = tokens[idx];
        if (p < 15) {
            float4 v = ((const float4*)(emb + (size_t)tok * E_DIM))[p];
            xs[4 * p]     = v.x;
            xs[4 * p + 1] = v.y;
            xs[4 * p + 2] = v.z;
            xs[4 * p + 3] = v.w;
        }
        __syncthreads();
        float s = 0.f;
        if (act) {
            s = bj;
            #pragma unroll
            for (int k = 0; k < E_DIM; ++k) s += wx[k] * xs[k];
        }
        gxp[((size_t)dir * T_LEN + t) * 256 + p] = s;
        __syncthreads();
    }
}

// ---------------------------------------------------------------------------
// Kernel 2: the sequential scan. grid = 2 (dir), block = 256 (4 waves).
// Lane (w,l): computes gate (l&3) pre-activation for dd = 15w + (l>>2).
// Quad combine via 3 independent shfl_xor (1,2,3) -> c,h update in gate==0
// lane. One barrier per step; h double-buffered in LDS.
// ---------------------------------------------------------------------------
__global__ __launch_bounds__(256) void scan_kernel(
    const float* __restrict__ WhhL,
    const float* __restrict__ WhhR,
    const float* __restrict__ gxp,
    float* __restrict__ hout)
{
    const int dir = blockIdx.x;
    const float* Whh = dir ? WhhR : WhhL;

    const int p = threadIdx.x;
    const int l = p & 63;
    const int w = p >> 6;
    const int gate = l & 3;
    const int dd = 15 * w + (l >> 2);
    const bool actv = (l < 60);
    const int j = gate * 60 + dd;

    float wh[D_DIM];
    if (actv) {
        const float4* row = (const float4*)(Whh + (size_t)j * D_DIM);
        #pragma unroll
        for (int i = 0; i < 15; ++i) {
            float4 v = row[i];
            wh[4 * i]     = v.x;
            wh[4 * i + 1] = v.y;
            wh[4 * i + 2] = v.z;
            wh[4 * i + 3] = v.w;
        }
    }

    __shared__ __align__(16) float hs[2][64];
    if (p < 64) { hs[0][p] = 0.f; hs[1][p] = 0.f; }

    float c = 0.f;
    const float* G = gxp + (size_t)dir * T_LEN * 256;

    float q0 = G[p];
    float q1 = G[256 + p];
    __syncthreads();

    for (int t = 0; t < T_LEN; ++t) {
        const float gx = q0;
        q0 = q1;
        q1 = (t + 2 < T_LEN) ? G[(size_t)(t + 2) * 256 + p] : 0.f;

        float hnew = 0.f;
        if (actv) {
            const float4* h4 = (const float4*)hs[t & 1];
            float a0 = gx, a1 = 0.f, a2 = 0.f, a3 = 0.f;
            #pragma unroll
            for (int r = 0; r < 15; ++r) {
                float4 hv = h4[r];
                a0 += wh[4 * r]     * hv.x;
                a1 += wh[4 * r + 1] * hv.y;
                a2 += wh[4 * r + 2] * hv.z;
                a3 += wh[4 * r + 3] * hv.w;
            }
            float a = (a0 + a1) + (a2 + a3);

            // gate 0,1,3: sigmoid ; gate 2: tanh (via sigmoid of 2x)
            const bool tg = (gate == 2);
            float z = tg ? (-2.f * a) : (-a);
            float e = __expf(z);
            float r = tg ? (2.f / (1.f + e) - 1.f) : (1.f / (1.f + e));

            // quad combine: lanes (base+0..3) hold (i,f,cg,o).
            // All three shuffles depend only on r -> single swizzle latency.
            float g1 = __shfl_xor(r, 1);   // lane0: f
            float g2 = __shfl_xor(r, 2);   // lane0: cg
            float g3 = __shfl_xor(r, 3);   // lane0: o
            if (gate == 0) {
                c = g1 * c + r * g2;                       // c = f*c + i*cg
                const float th = 1.f - 2.f / (__expf(2.f * c) + 1.f);
                hnew = g3 * th;                            // h = o*tanh(c)
            }
        }
        if (actv && gate == 0) hs[(t + 1) & 1][dd] = hnew;
        __syncthreads();
    }

    // final h is in hs[T_LEN & 1] == hs[0]
    if (p < 60) hout[dir * 64 + p] = hs[0][p];
}

// ---------------------------------------------------------------------------
// Kernel 3: out[c] = Why_L[c,:] @ h_L + Why_R[c,:] @ h_R   (5 fp32 outputs)
// ---------------------------------------------------------------------------
__global__ __launch_bounds__(64) void out_kernel(
    const float* __restrict__ WhyL,
    const float* __restrict__ WhyR,
    const float* __restrict__ hout,
    float* __restrict__ out)
{
    const int cI = threadIdx.x;
    if (cI < 5) {
        float s = 0.f;
        #pragma unroll
        for (int d = 0; d < D_DIM; ++d) {
            s += WhyL[cI * D_DIM + d] * hout[d];
            s += WhyR[cI * D_DIM + d] * hout[64 + d];
        }
        out[cI] = s;
    }
}

extern "C" void kernel_launch(void* const* d_in, const int* in_sizes, int n_in,
                              void* d_out, int out_size, void* d_ws, size_t ws_size,
                              hipStream_t stream) {
    const int*   tokens = (const int*)d_in[0];
    const float* emb    = (const float*)d_in[1];
    const float* WxhL   = (const float*)d_in[2];
    const float* WhhL   = (const float*)d_in[3];
    const float* bxhL   = (const float*)d_in[4];
    const float* bhhL   = (const float*)d_in[5];
    const float* WxhR   = (const float*)d_in[6];
    const float* WhhR   = (const float*)d_in[7];
    const float* bxhR   = (const float*)d_in[8];
    const float* bhhR   = (const float*)d_in[9];
    const float* WhyL   = (const float*)d_in[10];
    const float* WhyR   = (const float*)d_in[11];

    float* gxp  = (float*)d_ws;                       // 2*8192*256 floats = 16 MB
    float* hout = gxp + (size_t)2 * T_LEN * 256;      // 128 floats

    dim3 g1(T_LEN / TB, 2);
    gates_kernel<<<g1, 256, 0, stream>>>(tokens, emb, WxhL, bxhL, bhhL,
                                         WxhR, bxhR, bhhR, gxp);
    scan_kernel<<<2, 256, 0, stream>>>(WhhL, WhhR, gxp, hout);
    out_kernel<<<1, 64, 0, stream>>>(WhyL, WhyR, hout, (float*)d_out);
}

// Round 3
// 4465.569 us; speedup vs baseline: 1.0868x; 1.0868x over previous
//
#include <hip/hip_runtime.h>
#include <hip/hip_bf16.h>

// bidirLSTM: T=8192 seq, V=1e6 vocab, E=60 emb, D=60 hidden, C=5 out.
// ALL tensor inputs are float32 (per reference setup_inputs); tokens int32.
// Output: float32[5].
//
// kernel1: gates_x = emb[tokens] @ Wxh.T + (bxh+bhh), both directions,
//          stored permuted into the scan kernel's lane order (16 MB in d_ws).
// kernel2: sequential scan, 1 block/dir, 4 waves; lane quad holds the 4 gates
//          of one hidden unit d; h double-buffered in LDS.
//          R3: relaxed barrier (lgkmcnt-only, keeps gx prefetch in flight
//          across s_barrier — __syncthreads drains vmcnt(0) and cost ~900
//          cyc/step in R2), prefetch ring depth 4, v_rcp_f32 instead of
//          precise fp32 division.
// kernel3: out = Why_L @ h_L + Why_R @ h_R.

#define T_LEN 8192
#define E_DIM 60
#define D_DIM 60
#define TB    32       // timesteps per block in gates kernel

__device__ __forceinline__ float fast_rcp(float x) {
    return __builtin_amdgcn_rcpf(x);
}

// LDS-only barrier: waits LDS ops (lgkmcnt) but leaves global loads in
// flight across the barrier. Safe here because inter-wave communication in
// the scan loop goes exclusively through LDS.
__device__ __forceinline__ void lds_barrier() {
    asm volatile("s_waitcnt lgkmcnt(0)\n\ts_barrier" ::: "memory");
}

// ---------------------------------------------------------------------------
// Kernel 1: gxp[dir][t][p] = gates_x[dir][t][gate*60+dd] + (bxh+bhh)[j]
// where p = w*64 + l, gate = l&3, dd = 15*w + (l>>2)  (the scan's lane order).
// ---------------------------------------------------------------------------
__global__ __launch_bounds__(256) void gates_kernel(
    const int*   __restrict__ tokens,
    const float* __restrict__ emb,
    const float* __restrict__ WxhL,
    const float* __restrict__ bxhL,
    const float* __restrict__ bhhL,
    const float* __restrict__ WxhR,
    const float* __restrict__ bxhR,
    const float* __restrict__ bhhR,
    float* __restrict__ gxp)
{
    const int dir = blockIdx.y;
    const float* Wxh = dir ? WxhR : WxhL;
    const float* bxh = dir ? bxhR : bxhL;
    const float* bhh = dir ? bhhR : bhhL;

    const int p = threadIdx.x;
    const int w = p >> 6, l = p & 63;
    const int gate = l & 3;
    const int dd = 15 * w + (l >> 2);
    const bool act = (l < 60);
    const int j = gate * 60 + dd;

    float wx[E_DIM];
    float bj = 0.f;
    if (act) {
        const float4* row = (const float4*)(Wxh + (size_t)j * E_DIM); // 240 B stride, 16B-aligned
        #pragma unroll
        for (int i = 0; i < 15; ++i) {
            float4 v = row[i];
            wx[4 * i]     = v.x;
            wx[4 * i + 1] = v.y;
            wx[4 * i + 2] = v.z;
            wx[4 * i + 3] = v.w;
        }
        bj = bxh[j] + bhh[j];
    }

    __shared__ float xs[64];
    const int t0 = blockIdx.x * TB;
    for (int tt = 0; tt < TB; ++tt) {
        const int t = t0 + tt;
        const int idx = dir ? (T_LEN - 1 - t) : t;
        const int tok = tokens[idx];
        if (p < 15) {
            float4 v = ((const float4*)(emb + (size_t)tok * E_DIM))[p];
            xs[4 * p]     = v.x;
            xs[4 * p + 1] = v.y;
            xs[4 * p + 2] = v.z;
            xs[4 * p + 3] = v.w;
        }
        __syncthreads();
        float s = 0.f;
        if (act) {
            s = bj;
            #pragma unroll
            for (int k = 0; k < E_DIM; ++k) s += wx[k] * xs[k];
        }
        gxp[((size_t)dir * T_LEN + t) * 256 + p] = s;
        __syncthreads();
    }
}

// ---------------------------------------------------------------------------
// Kernel 2: the sequential scan. grid = 2 (dir), block = 256 (4 waves).
// Lane (w,l): computes gate (l&3) pre-activation for dd = 15w + (l>>2).
// Quad combine via 3 shfl_xor -> c,h update in gate==0 lane.
// One relaxed barrier per step; h double-buffered in LDS.
// ---------------------------------------------------------------------------
__global__ __launch_bounds__(256) void scan_kernel(
    const float* __restrict__ WhhL,
    const float* __restrict__ WhhR,
    const float* __restrict__ gxp,
    float* __restrict__ hout)
{
    const int dir = blockIdx.x;
    const float* Whh = dir ? WhhR : WhhL;

    const int p = threadIdx.x;
    const int l = p & 63;
    const int w = p >> 6;
    const int gate = l & 3;
    const int dd = 15 * w + (l >> 2);
    const bool actv = (l < 60);
    const int j = gate * 60 + dd;

    float wh[D_DIM];
    if (actv) {
        const float4* row = (const float4*)(Whh + (size_t)j * D_DIM);
        #pragma unroll
        for (int i = 0; i < 15; ++i) {
            float4 v = row[i];
            wh[4 * i]     = v.x;
            wh[4 * i + 1] = v.y;
            wh[4 * i + 2] = v.z;
            wh[4 * i + 3] = v.w;
        }
    }

    __shared__ __align__(16) float hs[2][64];
    if (p < 64) { hs[0][p] = 0.f; hs[1][p] = 0.f; }

    float c = 0.f;
    const float* G = gxp + (size_t)dir * T_LEN * 256;

    // prefetch ring, depth 4: at iter t we consume G[t] and issue G[t+4]
    float q0 = G[p];
    float q1 = G[256 + p];
    float q2 = G[2 * 256 + p];
    float q3 = G[3 * 256 + p];
    __syncthreads();

    for (int t = 0; t < T_LEN; ++t) {
        const float gx = q0;
        q0 = q1; q1 = q2; q2 = q3;
        q3 = (t + 4 < T_LEN) ? G[(size_t)(t + 4) * 256 + p] : 0.f;

        float hnew = 0.f;
        if (actv) {
            const float4* h4 = (const float4*)hs[t & 1];
            float a0 = gx, a1 = 0.f, a2 = 0.f, a3 = 0.f;
            #pragma unroll
            for (int r = 0; r < 15; ++r) {
                float4 hv = h4[r];
                a0 += wh[4 * r]     * hv.x;
                a1 += wh[4 * r + 1] * hv.y;
                a2 += wh[4 * r + 2] * hv.z;
                a3 += wh[4 * r + 3] * hv.w;
            }
            float a = (a0 + a1) + (a2 + a3);

            // gate 0,1,3: sigmoid ; gate 2: tanh (via sigmoid of 2x)
            const bool tg = (gate == 2);
            float z = tg ? (-2.f * a) : (-a);
            float e = __expf(z);
            float sg = fast_rcp(1.f + e);            // 1/(1+e)
            float r = tg ? (2.f * sg - 1.f) : sg;

            // quad combine: lanes (base+0..3) hold (i,f,cg,o);
            // all three shuffles depend only on r.
            float g1 = __shfl_xor(r, 1);   // lane0: f
            float g2 = __shfl_xor(r, 2);   // lane0: cg
            float g3 = __shfl_xor(r, 3);   // lane0: o
            if (gate == 0) {
                c = g1 * c + r * g2;                       // c = f*c + i*cg
                const float th = 1.f - 2.f * fast_rcp(__expf(2.f * c) + 1.f);
                hnew = g3 * th;                            // h = o*tanh(c)
            }
        }
        if (actv && gate == 0) hs[(t + 1) & 1][dd] = hnew;
        lds_barrier();
    }

    // final h is in hs[T_LEN & 1] == hs[0]
    if (p < 60) hout[dir * 64 + p] = hs[0][p];
}

// ---------------------------------------------------------------------------
// Kernel 3: out[c] = Why_L[c,:] @ h_L + Why_R[c,:] @ h_R   (5 fp32 outputs)
// ---------------------------------------------------------------------------
__global__ __launch_bounds__(64) void out_kernel(
    const float* __restrict__ WhyL,
    const float* __restrict__ WhyR,
    const float* __restrict__ hout,
    float* __restrict__ out)
{
    const int cI = threadIdx.x;
    if (cI < 5) {
        float s = 0.f;
        #pragma unroll
        for (int d = 0; d < D_DIM; ++d) {
            s += WhyL[cI * D_DIM + d] * hout[d];
            s += WhyR[cI * D_DIM + d] * hout[64 + d];
        }
        out[cI] = s;
    }
}

extern "C" void kernel_launch(void* const* d_in, const int* in_sizes, int n_in,
                              void* d_out, int out_size, void* d_ws, size_t ws_size,
                              hipStream_t stream) {
    const int*   tokens = (const int*)d_in[0];
    const float* emb    = (const float*)d_in[1];
    const float* WxhL   = (const float*)d_in[2];
    const float* WhhL   = (const float*)d_in[3];
    const float* bxhL   = (const float*)d_in[4];
    const float* bhhL   = (const float*)d_in[5];
    const float* WxhR   = (const float*)d_in[6];
    const float* WhhR   = (const float*)d_in[7];
    const float* bxhR   = (const float*)d_in[8];
    const float* bhhR   = (const float*)d_in[9];
    const float* WhyL   = (const float*)d_in[10];
    const float* WhyR   = (const float*)d_in[11];

    float* gxp  = (float*)d_ws;                       // 2*8192*256 floats = 16 MB
    float* hout = gxp + (size_t)2 * T_LEN * 256;      // 128 floats

    dim3 g1(T_LEN / TB, 2);
    gates_kernel<<<g1, 256, 0, stream>>>(tokens, emb, WxhL, bxhL, bhhL,
                                         WxhR, bxhR, bhhR, gxp);
    scan_kernel<<<2, 256, 0, stream>>>(WhhL, WhhR, gxp, hout);
    out_kernel<<<1, 64, 0, stream>>>(WhyL, WhyR, hout, (float*)d_out);
}

// Round 4
// 2957.804 us; speedup vs baseline: 1.6408x; 1.5098x over previous
//
#include <hip/hip_runtime.h>
#include <hip/hip_bf16.h>

// bidirLSTM: T=8192 seq, V=1e6 vocab, E=60 emb, D=60 hidden, C=5 out.
// ALL tensor inputs are float32 (per reference setup_inputs); tokens int32.
// Output: float32[5].
//
// R4 structure: quad-per-hidden-unit, K-split across the quad.
//   Lane (w,l): q = l&3 (K-chunk AND gate id), dd = 16*w + (l>>2) (unit).
//   Each lane reads only h[16q..16q+15] (h padded to 64) -> 4 ds_read_b128
//   per wave per step (was 15 broadcast b128: the LDS pipe at ~12 cyc/b128
//   was the R3 bottleneck, ~720 cyc/step/CU).
//   Quad reduce-scatter + gather via DPP quad_perm (VALU) — no ds_bpermute.
//   h double-buffered in LDS, one relaxed (lgkm-only) barrier per step.

#define T_LEN 8192
#define E_DIM 60
#define D_DIM 60
#define TB    32       // timesteps per block in gates kernel

__device__ __forceinline__ float fast_rcp(float x) {
    return __builtin_amdgcn_rcpf(x);
}

// LDS-only barrier: waits LDS ops (lgkmcnt) but leaves global loads in
// flight across the barrier. Safe: inter-wave communication in the scan
// loop goes exclusively through LDS.
__device__ __forceinline__ void lds_barrier() {
    asm volatile("s_waitcnt lgkmcnt(0)\n\ts_barrier" ::: "memory");
}

// DPP quad_perm cross-lane move (stays on the VALU, not the LDS unit).
// ctrl = p0 | p1<<2 | p2<<4 | p3<<6.
#define QP_XOR1 0xB1   // [1,0,3,2]
#define QP_XOR2 0x4E   // [2,3,0,1]
#define QP_XOR3 0x1B   // [3,2,1,0]
template <int CTRL>
__device__ __forceinline__ float qperm(float x) {
    union { float f; int i; } u, r;
    u.f = x;
    r.i = __builtin_amdgcn_update_dpp(0, u.i, CTRL, 0xF, 0xF, true);
    return r.f;
}

// ---------------------------------------------------------------------------
// Kernel 1: gxp[dir][t][p] = gates_x[dir][t][gate*60+dd] + (bxh+bhh)[j]
// where p = w*64 + l, gate = l&3, dd = 16*w + (l>>2)  (scan lane order).
// ---------------------------------------------------------------------------
__global__ __launch_bounds__(256) void gates_kernel(
    const int*   __restrict__ tokens,
    const float* __restrict__ emb,
    const float* __restrict__ WxhL,
    const float* __restrict__ bxhL,
    const float* __restrict__ bhhL,
    const float* __restrict__ WxhR,
    const float* __restrict__ bxhR,
    const float* __restrict__ bhhR,
    float* __restrict__ gxp)
{
    const int dir = blockIdx.y;
    const float* Wxh = dir ? WxhR : WxhL;
    const float* bxh = dir ? bxhR : bxhL;
    const float* bhh = dir ? bhhR : bhhL;

    const int p = threadIdx.x;
    const int w = p >> 6, l = p & 63;
    const int gate = l & 3;
    const int dd = 16 * w + (l >> 2);
    const bool act = (dd < D_DIM);
    const int j = gate * 60 + (act ? dd : 0);

    float wx[E_DIM];
    float bj = 0.f;
    if (act) {
        const float4* row = (const float4*)(Wxh + (size_t)j * E_DIM); // 240 B stride, 16B-aligned
        #pragma unroll
        for (int i = 0; i < 15; ++i) {
            float4 v = row[i];
            wx[4 * i]     = v.x;
            wx[4 * i + 1] = v.y;
            wx[4 * i + 2] = v.z;
            wx[4 * i + 3] = v.w;
        }
        bj = bxh[j] + bhh[j];
    }

    __shared__ float xs[64];
    const int t0 = blockIdx.x * TB;
    for (int tt = 0; tt < TB; ++tt) {
        const int t = t0 + tt;
        const int idx = dir ? (T_LEN - 1 - t) : t;
        const int tok = tokens[idx];
        if (p < 15) {
            float4 v = ((const float4*)(emb + (size_t)tok * E_DIM))[p];
            xs[4 * p]     = v.x;
            xs[4 * p + 1] = v.y;
            xs[4 * p + 2] = v.z;
            xs[4 * p + 3] = v.w;
        }
        __syncthreads();
        float s = 0.f;
        if (act) {
            s = bj;
            #pragma unroll
            for (int k = 0; k < E_DIM; ++k) s += wx[k] * xs[k];
        }
        gxp[((size_t)dir * T_LEN + t) * 256 + p] = s;
        __syncthreads();
    }
}

// ---------------------------------------------------------------------------
// Kernel 2: sequential scan. grid = 2 (dir), block = 256 (4 waves).
// ---------------------------------------------------------------------------
__global__ __launch_bounds__(256) void scan_kernel(
    const float* __restrict__ WhhL,
    const float* __restrict__ WhhR,
    const float* __restrict__ gxp,
    float* __restrict__ hout)
{
    const int dir = blockIdx.x;
    const float* Whh = dir ? WhhR : WhhL;

    const int p = threadIdx.x;
    const int l = p & 63;
    const int w = p >> 6;
    const int q = l & 3;            // K-chunk id AND gate id within the quad
    const int dd = 16 * w + (l >> 2);
    const bool actv = (dd < D_DIM);

    // Per-lane weights: Whh[g*60+dd][16q + i] for g=0..3, i=0..15 (0-padded).
    float whg[4][16];
    #pragma unroll
    for (int g = 0; g < 4; ++g) {
        #pragma unroll
        for (int i = 0; i < 16; ++i) {
            const int k = 16 * q + i;
            whg[g][i] = (actv && k < D_DIM)
                        ? Whh[(size_t)(g * 60 + dd) * D_DIM + k] : 0.f;
        }
    }

    __shared__ __align__(16) float hs[2][64];   // h padded to 64, pad stays 0
    if (p < 64) { hs[0][p] = 0.f; hs[1][p] = 0.f; }

    float c = 0.f;                   // live in q==0 lanes only
    const float* G = gxp + (size_t)dir * T_LEN * 256;

    // prefetch ring, depth 4
    float q0 = G[p];
    float q1 = G[256 + p];
    float q2 = G[2 * 256 + p];
    float q3 = G[3 * 256 + p];
    __syncthreads();

    for (int t = 0; t < T_LEN; ++t) {
        const float gx = q0;
        q0 = q1; q1 = q2; q2 = q3;
        q3 = (t + 4 < T_LEN) ? G[(size_t)(t + 4) * 256 + p] : 0.f;

        // ---- partial dot products over this lane's K-chunk, all 4 gates ----
        const float4* h4 = (const float4*)(hs[t & 1] + 16 * q);
        float p0 = (q == 0) ? gx : 0.f;
        float p1 = (q == 1) ? gx : 0.f;
        float p2 = (q == 2) ? gx : 0.f;
        float p3 = (q == 3) ? gx : 0.f;
        #pragma unroll
        for (int i = 0; i < 4; ++i) {
            float4 hv = h4[i];
            p0 += whg[0][4*i] * hv.x; p0 += whg[0][4*i+1] * hv.y;
            p0 += whg[0][4*i+2] * hv.z; p0 += whg[0][4*i+3] * hv.w;
            p1 += whg[1][4*i] * hv.x; p1 += whg[1][4*i+1] * hv.y;
            p1 += whg[1][4*i+2] * hv.z; p1 += whg[1][4*i+3] * hv.w;
            p2 += whg[2][4*i] * hv.x; p2 += whg[2][4*i+1] * hv.y;
            p2 += whg[2][4*i+2] * hv.z; p2 += whg[2][4*i+3] * hv.w;
            p3 += whg[3][4*i] * hv.x; p3 += whg[3][4*i+1] * hv.y;
            p3 += whg[3][4*i+2] * hv.z; p3 += whg[3][4*i+3] * hv.w;
        }

        // ---- quad reduce-scatter via DPP: lane q ends with gate-q sum ----
        const bool b0 = (q & 1) != 0;
        const bool b1 = (q & 2) != 0;
        float sA = b0 ? p0 : p1;
        float a01 = (b0 ? p1 : p0) + qperm<QP_XOR1>(sA);  // my gate in {0,1}
        float sB = b0 ? p2 : p3;
        float b23 = (b0 ? p3 : p2) + qperm<QP_XOR1>(sB);  // my gate in {2,3}
        float sC = b1 ? a01 : b23;
        float a  = (b1 ? b23 : a01) + qperm<QP_XOR2>(sC); // gate-q total

        // ---- activate own gate: q==2 -> tanh, else sigmoid ----
        const bool tg = (q == 2);
        float z  = tg ? (-2.f * a) : (-a);
        float e  = __expf(z);
        float sg = fast_rcp(1.f + e);
        float r  = tg ? (2.f * sg - 1.f) : sg;

        // ---- gather f,cg,o into lane 0 of the quad (DPP) ----
        float f_ = qperm<QP_XOR1>(r);   // lane0: gate1
        float cg = qperm<QP_XOR2>(r);   // lane0: gate2
        float o_ = qperm<QP_XOR3>(r);   // lane0: gate3

        // ---- c/h update (valid in q==0 lanes; others compute garbage) ----
        c = f_ * c + r * cg;
        const float th = 1.f - 2.f * fast_rcp(__expf(2.f * c) + 1.f);
        const float hnew = o_ * th;

        if (actv && q == 0) hs[(t + 1) & 1][dd] = hnew;
        lds_barrier();
    }

    // final h is in hs[T_LEN & 1] == hs[0]
    if (p < D_DIM) hout[dir * 64 + p] = hs[0][p];
}

// ---------------------------------------------------------------------------
// Kernel 3: out[c] = Why_L[c,:] @ h_L + Why_R[c,:] @ h_R   (5 fp32 outputs)
// ---------------------------------------------------------------------------
__global__ __launch_bounds__(64) void out_kernel(
    const float* __restrict__ WhyL,
    const float* __restrict__ WhyR,
    const float* __restrict__ hout,
    float* __restrict__ out)
{
    const int cI = threadIdx.x;
    if (cI < 5) {
        float s = 0.f;
        #pragma unroll
        for (int d = 0; d < D_DIM; ++d) {
            s += WhyL[cI * D_DIM + d] * hout[d];
            s += WhyR[cI * D_DIM + d] * hout[64 + d];
        }
        out[cI] = s;
    }
}

extern "C" void kernel_launch(void* const* d_in, const int* in_sizes, int n_in,
                              void* d_out, int out_size, void* d_ws, size_t ws_size,
                              hipStream_t stream) {
    const int*   tokens = (const int*)d_in[0];
    const float* emb    = (const float*)d_in[1];
    const float* WxhL   = (const float*)d_in[2];
    const float* WhhL   = (const float*)d_in[3];
    const float* bxhL   = (const float*)d_in[4];
    const float* bhhL   = (const float*)d_in[5];
    const float* WxhR   = (const float*)d_in[6];
    const float* WhhR   = (const float*)d_in[7];
    const float* bxhR   = (const float*)d_in[8];
    const float* bhhR   = (const float*)d_in[9];
    const float* WhyL   = (const float*)d_in[10];
    const float* WhyR   = (const float*)d_in[11];

    float* gxp  = (float*)d_ws;                       // 2*8192*256 floats = 16 MB
    float* hout = gxp + (size_t)2 * T_LEN * 256;      // 128 floats

    dim3 g1(T_LEN / TB, 2);
    gates_kernel<<<g1, 256, 0, stream>>>(tokens, emb, WxhL, bxhL, bhhL,
                                         WxhR, bxhR, bhhR, gxp);
    scan_kernel<<<2, 256, 0, stream>>>(WhhL, WhhR, gxp, hout);
    out_kernel<<<1, 64, 0, stream>>>(WhyL, WhyR, hout, (float*)d_out);
}